// Round 8
// baseline (117.602 us; speedup 1.0000x reference)
//
#include <hip/hip_runtime.h>

#define HH 4096
#define WW 4096
#define TS 512
#define NBINS 256
#define NT 64
#define NCHUNK 32
#define NBLK (NT * NCHUNK)
#define PLANE (HH * WW)

typedef float vf4 __attribute__((ext_vector_type(4)));

// ---------- helpers ----------
__device__ __forceinline__ float wred_min(float v) {
#pragma unroll
    for (int o = 32; o > 0; o >>= 1) v = fminf(v, __shfl_down(v, o, 64));
    return v;
}
__device__ __forceinline__ float wred_max(float v) {
#pragma unroll
    for (int o = 32; o > 0; o >>= 1) v = fmaxf(v, __shfl_down(v, o, 64));
    return v;
}
__device__ __forceinline__ float wred_sum(float v) {
#pragma unroll
    for (int o = 32; o > 0; o >>= 1) v += __shfl_down(v, o, 64);
    return v;
}

// ==================== kernel 1: per-block partial histogram + min/max ====================
// grid: 64 tiles * 32 row-chunks = 2048 blocks, 256 threads.
// Each block: 16 rows x 512 cols of one tile (8192 px), float4 loads.
// 4 private LDS hist copies (one per wave) -> no cross-wave same-address serialization.
#define HIST_LANE(comp)                                              \
    {                                                                \
        float l = (a.comp + b.comp + c.comp) / 3.0f;                 \
        vmin = fminf(vmin, l);                                       \
        vmax = fmaxf(vmax, l);                                       \
        int bb = (int)(l * 256.0f);                                  \
        bb = bb < 0 ? 0 : (bb > 255 ? 255 : bb);                     \
        atomicAdd(&sh[bb], 1u);                                      \
    }

__global__ __launch_bounds__(256) void k_hist_p(const float* __restrict__ img,
                                                unsigned* __restrict__ part,
                                                float* __restrict__ pmin,
                                                float* __restrict__ pmax) {
    __shared__ unsigned shh[4][NBINS + 1];
    __shared__ float smin[4], smax[4];
    int tid = threadIdx.x;
    shh[0][tid] = 0u;
    shh[1][tid] = 0u;
    shh[2][tid] = 0u;
    shh[3][tid] = 0u;
    __syncthreads();

    unsigned* sh = shh[tid >> 6];  // per-wave private copy

    int bx = blockIdx.x;
    int t = bx >> 5;        // tile 0..63
    int chunk = bx & 31;    // row chunk 0..31
    int row0 = (t >> 3) * TS + chunk * 16;
    int cb4 = (t & 7) * (TS / 4);  // float4 col base

    const float4* p0 = (const float4*)(img);
    const float4* p1 = (const float4*)(img + PLANE);
    const float4* p2 = (const float4*)(img + 2 * PLANE);

    int colv = tid & 127;
    int rsub = tid >> 7;
    float vmin = 1e30f, vmax = -1e30f;

#pragma unroll
    for (int it = 0; it < 8; ++it) {
        int r = row0 + (it << 1) + rsub;
        size_t idx4 = (size_t)r * (WW / 4) + cb4 + colv;
        float4 a = p0[idx4];
        float4 b = p1[idx4];
        float4 c = p2[idx4];
        HIST_LANE(x)
        HIST_LANE(y)
        HIST_LANE(z)
        HIST_LANE(w)
    }

    // block min/max reduce
    float wmn = wred_min(vmin), wmx = wred_max(vmax);
    if ((tid & 63) == 0) { smin[tid >> 6] = wmn; smax[tid >> 6] = wmx; }
    __syncthreads();
    if (tid == 0) {
        pmin[bx] = fminf(fminf(smin[0], smin[1]), fminf(smin[2], smin[3]));
        pmax[bx] = fmaxf(fmaxf(smax[0], smax[1]), fmaxf(smax[2], smax[3]));
    }
    part[(size_t)bx * NBINS + tid] =
        shh[0][tid] + shh[1][tid] + shh[2][tid] + shh[3][tid];
}

// ==================== kernel 2: reduce partials + clip + cdf per tile ====================
__global__ __launch_bounds__(256) void k_cdf_p(const unsigned* __restrict__ part,
                                               const float* __restrict__ pmin,
                                               const float* __restrict__ pmax,
                                               const float* __restrict__ alphas,
                                               float* __restrict__ cdfa,
                                               float* __restrict__ params) {
    __shared__ float wtot[4];
    __shared__ float wsums[4];
    __shared__ float sminmax[2];
    int t = blockIdx.x, tid = threadIdx.x;

    // exact integer reduction of 32 partials (all counts < 2^24: f32-exact)
    float h = 0.0f;
#pragma unroll
    for (int c = 0; c < NCHUNK; ++c)
        h += (float)part[((size_t)(t * NCHUNK + c)) * NBINS + tid];

    const float cl = 4096.0f;  // int(4.0 * 512*512 / 256)

    float ex = fmaxf(h - cl, 0.0f);
    float w = wred_sum(ex);
    if ((tid & 63) == 0) wsums[tid >> 6] = w;

    // min/max reduce on wave 0
    if (tid < 64) {
        float m = (tid < NCHUNK) ? pmin[t * NCHUNK + tid] : 1e30f;
        float M = (tid < NCHUNK) ? pmax[t * NCHUNK + tid] : -1e30f;
        m = wred_min(m);
        M = wred_max(M);
        if (tid == 0) { sminmax[0] = m; sminmax[1] = M; }
    }
    __syncthreads();
    float excess = wsums[0] + wsums[1] + wsums[2] + wsums[3];

    float hc = fminf(h, cl) + excess / 256.0f;

    // wave-level inclusive scan (shfl), then add wave offsets
    int lane = tid & 63, wv = tid >> 6;
    float v = hc;
#pragma unroll
    for (int off = 1; off < 64; off <<= 1) {
        float u = __shfl_up(v, off, 64);
        if (lane >= off) v += u;
    }
    if (lane == 63) wtot[wv] = v;
    __syncthreads();
    float base = 0.0f;
    if (wv > 0) base += wtot[0];
    if (wv > 1) base += wtot[1];
    if (wv > 2) base += wtot[2];
    float cdf = base + v;
    float total = ((wtot[0] + wtot[1]) + wtot[2]) + wtot[3];

    float alpha = 0.5f + 0.5f * alphas[t];
    cdfa[t * NBINS + tid] = alpha * (cdf / total);

    if (tid == 0) {
        float tmin = sminmax[0];
        float tmax = sminmax[1];
        bool valid = tmin < tmax;
        params[t * 4 + 0] = tmin;
        params[t * 4 + 1] = valid ? (tmax - tmin) : 1.0f;  // true denominator
        params[t * 4 + 2] = 1.0f - alpha;
        params[t * 4 + 3] = valid ? 1.0f : 0.0f;
    }
}

// ==================== kernel 3: tile-mapped apply, cdf table in LDS ====================
// Identical to R7 EXCEPT: regular stores instead of nontemporal (single-variable
// ablation: does the NT path write slower than the cached L2 write path?).
#define APPLY_LANE2(comp)                                            \
    {                                                                \
        float l = (a.comp + b.comp + c.comp) / 3.0f;                 \
        float nrm = (l - tmin) / den;                                \
        int ix = (int)(nrm * 255.0f);                                \
        ix = ix < 0 ? 0 : (ix > 255 ? 255 : ix);                     \
        float enh = sc[ix] + oma * l;                                \
        float e0, e1, e2;                                            \
        if (l > 1e-5f) {                                             \
            float rinv = enh * __builtin_amdgcn_rcpf(l);             \
            e0 = a.comp * rinv;                                      \
            e1 = b.comp * rinv;                                      \
            e2 = c.comp * rinv;                                      \
        } else {                                                     \
            e0 = enh; e1 = enh; e2 = enh;                            \
        }                                                            \
        if (vflag == 0.0f) { e0 = a.comp; e1 = b.comp; e2 = c.comp; }\
        r0.comp = fminf(fmaxf(e0, 0.0f), 1.0f);                      \
        r1.comp = fminf(fmaxf(e1, 0.0f), 1.0f);                      \
        r2.comp = fminf(fmaxf(e2, 0.0f), 1.0f);                      \
    }

__global__ __launch_bounds__(256) void k_apply_t(const float* __restrict__ img,
                                                 float* __restrict__ out,
                                                 const float* __restrict__ cdfa,
                                                 const float* __restrict__ params) {
    __shared__ float sc[NBINS];
    __shared__ float sp[4];
    int tid = threadIdx.x;
    int bx = blockIdx.x;
    int t = bx >> 5;
    int chunk = bx & 31;

    sc[tid] = cdfa[(t << 8) + tid];
    if (tid < 4) sp[tid] = params[(t << 2) + tid];
    __syncthreads();

    float tmin = sp[0], den = sp[1], oma = sp[2], vflag = sp[3];

    int row0 = (t >> 3) * TS + chunk * 16;
    int cb4 = (t & 7) * (TS / 4);

    const float4* p0 = (const float4*)(img);
    const float4* p1 = (const float4*)(img + PLANE);
    const float4* p2 = (const float4*)(img + 2 * PLANE);
    float4* o0 = (float4*)(out);
    float4* o1 = (float4*)(out + PLANE);
    float4* o2 = (float4*)(out + 2 * PLANE);

    int colv = tid & 127;
    int rsub = tid >> 7;

#pragma unroll
    for (int it = 0; it < 8; ++it) {
        int r = row0 + (it << 1) + rsub;
        size_t idx4 = (size_t)r * (WW / 4) + cb4 + colv;
        float4 a = p0[idx4];
        float4 b = p1[idx4];
        float4 c = p2[idx4];
        float4 r0, r1, r2;
        APPLY_LANE2(x)
        APPLY_LANE2(y)
        APPLY_LANE2(z)
        APPLY_LANE2(w)
        o0[idx4] = r0;
        o1[idx4] = r1;
        o2[idx4] = r2;
    }
}

// ==================== FALLBACK PATH (ws too small: atomics + memset) ====================

__global__ __launch_bounds__(256) void k_hist_a(const float* __restrict__ img,
                                                unsigned* __restrict__ ghist,
                                                unsigned* __restrict__ minu,
                                                unsigned* __restrict__ maxu) {
    __shared__ unsigned shf[NBINS];
    __shared__ float smin[4], smax[4];
    int tid = threadIdx.x;
    shf[tid] = 0u;
    __syncthreads();
    unsigned* sh = shf;
    int bx = blockIdx.x;
    int t = bx >> 5;
    int chunk = bx & 31;
    int row0 = (t >> 3) * TS + chunk * 16;
    int cb4 = (t & 7) * (TS / 4);
    const float4* p0 = (const float4*)(img);
    const float4* p1 = (const float4*)(img + PLANE);
    const float4* p2 = (const float4*)(img + 2 * PLANE);
    int colv = tid & 127;
    int rsub = tid >> 7;
    float vmin = 1e30f, vmax = -1e30f;
#pragma unroll
    for (int it = 0; it < 8; ++it) {
        int r = row0 + (it << 1) + rsub;
        size_t idx4 = (size_t)r * (WW / 4) + cb4 + colv;
        float4 a = p0[idx4];
        float4 b = p1[idx4];
        float4 c = p2[idx4];
        HIST_LANE(x)
        HIST_LANE(y)
        HIST_LANE(z)
        HIST_LANE(w)
    }
    float wmn = wred_min(vmin), wmx = wred_max(vmax);
    if ((tid & 63) == 0) { smin[tid >> 6] = wmn; smax[tid >> 6] = wmx; }
    __syncthreads();
    if (tid == 0) {
        float m = fminf(fminf(smin[0], smin[1]), fminf(smin[2], smin[3]));
        float M = fmaxf(fmaxf(smax[0], smax[1]), fmaxf(smax[2], smax[3]));
        atomicMax(&minu[t], 0x3F800000u - __float_as_uint(m));
        atomicMax(&maxu[t], __float_as_uint(M));
    }
    atomicAdd(&ghist[t * NBINS + tid], shf[tid]);
}

__global__ __launch_bounds__(256) void k_cdf_a(const unsigned* __restrict__ ghist,
                                               const unsigned* __restrict__ minu,
                                               const unsigned* __restrict__ maxu,
                                               const float* __restrict__ alphas,
                                               float* __restrict__ cdfa,
                                               float* __restrict__ params) {
    __shared__ float wtot[4];
    __shared__ float wsums[4];
    int t = blockIdx.x, tid = threadIdx.x;
    float h = (float)ghist[t * NBINS + tid];
    const float cl = 4096.0f;
    float ex = fmaxf(h - cl, 0.0f);
    float w = wred_sum(ex);
    if ((tid & 63) == 0) wsums[tid >> 6] = w;
    __syncthreads();
    float excess = wsums[0] + wsums[1] + wsums[2] + wsums[3];
    float hc = fminf(h, cl) + excess / 256.0f;

    int lane = tid & 63, wv = tid >> 6;
    float v = hc;
#pragma unroll
    for (int off = 1; off < 64; off <<= 1) {
        float u = __shfl_up(v, off, 64);
        if (lane >= off) v += u;
    }
    if (lane == 63) wtot[wv] = v;
    __syncthreads();
    float base = 0.0f;
    if (wv > 0) base += wtot[0];
    if (wv > 1) base += wtot[1];
    if (wv > 2) base += wtot[2];
    float cdf = base + v;
    float total = ((wtot[0] + wtot[1]) + wtot[2]) + wtot[3];

    float alpha = 0.5f + 0.5f * alphas[t];
    cdfa[t * NBINS + tid] = alpha * (cdf / total);

    if (tid == 0) {
        float tmin = __uint_as_float(0x3F800000u - minu[t]);
        float tmax = __uint_as_float(maxu[t]);
        bool valid = tmin < tmax;
        params[t * 4 + 0] = tmin;
        params[t * 4 + 1] = valid ? (tmax - tmin) : 1.0f;
        params[t * 4 + 2] = 1.0f - alpha;
        params[t * 4 + 3] = valid ? 1.0f : 0.0f;
    }
}

extern "C" void kernel_launch(void* const* d_in, const int* in_sizes, int n_in,
                              void* d_out, int out_size, void* d_ws, size_t ws_size,
                              hipStream_t stream) {
    const float* img = (const float*)d_in[0];
    const float* alphas = (const float*)d_in[1];
    float* out = (float*)d_out;

    // partials layout (4B units):
    // part[2048*256] | pmin[2048] | pmax[2048] | cdfa[64*256] | params[64*4]
    const size_t need = ((size_t)NBLK * NBINS + 2 * NBLK + NT * NBINS + NT * 4) * 4;

    if (ws_size >= need) {
        unsigned* part = (unsigned*)d_ws;
        float* pmin = (float*)(part + (size_t)NBLK * NBINS);
        float* pmax = pmin + NBLK;
        float* cdfa = pmax + NBLK;
        float* params = cdfa + NT * NBINS;

        k_hist_p<<<NBLK, 256, 0, stream>>>(img, part, pmin, pmax);
        k_cdf_p<<<NT, NBINS, 0, stream>>>(part, pmin, pmax, alphas, cdfa, params);
        k_apply_t<<<NBLK, 256, 0, stream>>>(img, out, cdfa, params);
    } else {
        // fallback: hist[64*256] | minu[64] | maxu[64] | pad[64] | cdfa[64*256] | params[64*4]
        unsigned* hist = (unsigned*)d_ws;
        unsigned* minu = hist + NT * NBINS;
        unsigned* maxu = minu + NT;
        float* cdfa = (float*)(maxu + 2 * NT);
        float* params = cdfa + NT * NBINS;

        (void)hipMemsetAsync(d_ws, 0, (size_t)(NT * NBINS + 3 * NT) * 4, stream);
        k_hist_a<<<NBLK, 256, 0, stream>>>(img, hist, minu, maxu);
        k_cdf_a<<<NT, NBINS, 0, stream>>>(hist, minu, maxu, alphas, cdfa, params);
        k_apply_t<<<NBLK, 256, 0, stream>>>(img, out, cdfa, params);
    }
}

// Round 9
// 95.589 us; speedup vs baseline: 1.2303x; 1.2303x over previous
//
#include <hip/hip_runtime.h>

#define HH 4096
#define WW 4096
#define TS 512
#define NBINS 256
#define NT 64
#define NCHUNK 32
#define NBLK (NT * NCHUNK)
#define PLANE (HH * WW)

typedef float vf4 __attribute__((ext_vector_type(4)));

// ---------- helpers ----------
__device__ __forceinline__ float wred_min(float v) {
#pragma unroll
    for (int o = 32; o > 0; o >>= 1) v = fminf(v, __shfl_down(v, o, 64));
    return v;
}
__device__ __forceinline__ float wred_max(float v) {
#pragma unroll
    for (int o = 32; o > 0; o >>= 1) v = fmaxf(v, __shfl_down(v, o, 64));
    return v;
}
__device__ __forceinline__ float wred_sum(float v) {
#pragma unroll
    for (int o = 32; o > 0; o >>= 1) v += __shfl_down(v, o, 64);
    return v;
}

// ==================== kernel 1: per-block partial histogram + min/max ====================
// grid: 64 tiles * 32 row-chunks = 2048 blocks, 256 threads.
// Each block: 16 rows x 512 cols of one tile (8192 px), float4 loads.
// 4 private LDS hist copies (one per wave) -> no cross-wave same-address serialization.
#define HIST_LANE(comp)                                              \
    {                                                                \
        float l = (a.comp + b.comp + c.comp) / 3.0f;                 \
        vmin = fminf(vmin, l);                                       \
        vmax = fmaxf(vmax, l);                                       \
        int bb = (int)(l * 256.0f);                                  \
        bb = bb < 0 ? 0 : (bb > 255 ? 255 : bb);                     \
        atomicAdd(&sh[bb], 1u);                                      \
    }

__global__ __launch_bounds__(256) void k_hist_p(const float* __restrict__ img,
                                                unsigned* __restrict__ part,
                                                float* __restrict__ pmin,
                                                float* __restrict__ pmax) {
    __shared__ unsigned shh[4][NBINS + 1];
    __shared__ float smin[4], smax[4];
    int tid = threadIdx.x;
    shh[0][tid] = 0u;
    shh[1][tid] = 0u;
    shh[2][tid] = 0u;
    shh[3][tid] = 0u;
    __syncthreads();

    unsigned* sh = shh[tid >> 6];  // per-wave private copy

    int bx = blockIdx.x;
    int t = bx >> 5;        // tile 0..63
    int chunk = bx & 31;    // row chunk 0..31
    int row0 = (t >> 3) * TS + chunk * 16;
    int cb4 = (t & 7) * (TS / 4);  // float4 col base

    const float4* p0 = (const float4*)(img);
    const float4* p1 = (const float4*)(img + PLANE);
    const float4* p2 = (const float4*)(img + 2 * PLANE);

    int colv = tid & 127;
    int rsub = tid >> 7;
    float vmin = 1e30f, vmax = -1e30f;

#pragma unroll
    for (int it = 0; it < 8; ++it) {
        int r = row0 + (it << 1) + rsub;
        size_t idx4 = (size_t)r * (WW / 4) + cb4 + colv;
        float4 a = p0[idx4];
        float4 b = p1[idx4];
        float4 c = p2[idx4];
        HIST_LANE(x)
        HIST_LANE(y)
        HIST_LANE(z)
        HIST_LANE(w)
    }

    // block min/max reduce
    float wmn = wred_min(vmin), wmx = wred_max(vmax);
    if ((tid & 63) == 0) { smin[tid >> 6] = wmn; smax[tid >> 6] = wmx; }
    __syncthreads();
    if (tid == 0) {
        pmin[bx] = fminf(fminf(smin[0], smin[1]), fminf(smin[2], smin[3]));
        pmax[bx] = fmaxf(fmaxf(smax[0], smax[1]), fmaxf(smax[2], smax[3]));
    }
    part[(size_t)bx * NBINS + tid] =
        shh[0][tid] + shh[1][tid] + shh[2][tid] + shh[3][tid];
}

// ==================== kernel 2: reduce partials + clip + cdf per tile ====================
__global__ __launch_bounds__(256) void k_cdf_p(const unsigned* __restrict__ part,
                                               const float* __restrict__ pmin,
                                               const float* __restrict__ pmax,
                                               const float* __restrict__ alphas,
                                               float* __restrict__ cdfa,
                                               float* __restrict__ params) {
    __shared__ float wtot[4];
    __shared__ float wsums[4];
    __shared__ float sminmax[2];
    int t = blockIdx.x, tid = threadIdx.x;

    // exact integer reduction of 32 partials (all counts < 2^24: f32-exact)
    float h = 0.0f;
#pragma unroll
    for (int c = 0; c < NCHUNK; ++c)
        h += (float)part[((size_t)(t * NCHUNK + c)) * NBINS + tid];

    const float cl = 4096.0f;  // int(4.0 * 512*512 / 256)

    float ex = fmaxf(h - cl, 0.0f);
    float w = wred_sum(ex);
    if ((tid & 63) == 0) wsums[tid >> 6] = w;

    // min/max reduce on wave 0
    if (tid < 64) {
        float m = (tid < NCHUNK) ? pmin[t * NCHUNK + tid] : 1e30f;
        float M = (tid < NCHUNK) ? pmax[t * NCHUNK + tid] : -1e30f;
        m = wred_min(m);
        M = wred_max(M);
        if (tid == 0) { sminmax[0] = m; sminmax[1] = M; }
    }
    __syncthreads();
    float excess = wsums[0] + wsums[1] + wsums[2] + wsums[3];

    float hc = fminf(h, cl) + excess / 256.0f;

    // wave-level inclusive scan (shfl), then add wave offsets
    int lane = tid & 63, wv = tid >> 6;
    float v = hc;
#pragma unroll
    for (int off = 1; off < 64; off <<= 1) {
        float u = __shfl_up(v, off, 64);
        if (lane >= off) v += u;
    }
    if (lane == 63) wtot[wv] = v;
    __syncthreads();
    float base = 0.0f;
    if (wv > 0) base += wtot[0];
    if (wv > 1) base += wtot[1];
    if (wv > 2) base += wtot[2];
    float cdf = base + v;
    float total = ((wtot[0] + wtot[1]) + wtot[2]) + wtot[3];

    float alpha = 0.5f + 0.5f * alphas[t];
    cdfa[t * NBINS + tid] = alpha * (cdf / total);

    if (tid == 0) {
        float tmin = sminmax[0];
        float tmax = sminmax[1];
        bool valid = tmin < tmax;
        params[t * 4 + 0] = tmin;
        params[t * 4 + 1] = valid ? (tmax - tmin) : 1.0f;  // true denominator
        params[t * 4 + 2] = 1.0f - alpha;
        params[t * 4 + 3] = valid ? 1.0f : 0.0f;
    }
}

// ==================== kernel 3: tile-mapped apply, cdf table in LDS, NT stores ====================
#define APPLY_LANE2(comp)                                            \
    {                                                                \
        float l = (a.comp + b.comp + c.comp) / 3.0f;                 \
        float nrm = (l - tmin) / den;                                \
        int ix = (int)(nrm * 255.0f);                                \
        ix = ix < 0 ? 0 : (ix > 255 ? 255 : ix);                     \
        float enh = sc[ix] + oma * l;                                \
        float e0, e1, e2;                                            \
        if (l > 1e-5f) {                                             \
            float rinv = enh * __builtin_amdgcn_rcpf(l);             \
            e0 = a.comp * rinv;                                      \
            e1 = b.comp * rinv;                                      \
            e2 = c.comp * rinv;                                      \
        } else {                                                     \
            e0 = enh; e1 = enh; e2 = enh;                            \
        }                                                            \
        if (vflag == 0.0f) { e0 = a.comp; e1 = b.comp; e2 = c.comp; }\
        r0.comp = fminf(fmaxf(e0, 0.0f), 1.0f);                      \
        r1.comp = fminf(fmaxf(e1, 0.0f), 1.0f);                      \
        r2.comp = fminf(fmaxf(e2, 0.0f), 1.0f);                      \
    }

__global__ __launch_bounds__(256) void k_apply_t(const float* __restrict__ img,
                                                 float* __restrict__ out,
                                                 const float* __restrict__ cdfa,
                                                 const float* __restrict__ params) {
    __shared__ float sc[NBINS];
    __shared__ float sp[4];
    int tid = threadIdx.x;
    int bx = blockIdx.x;
    int t = bx >> 5;
    int chunk = bx & 31;

    sc[tid] = cdfa[(t << 8) + tid];
    if (tid < 4) sp[tid] = params[(t << 2) + tid];
    __syncthreads();

    float tmin = sp[0], den = sp[1], oma = sp[2], vflag = sp[3];

    int row0 = (t >> 3) * TS + chunk * 16;
    int cb4 = (t & 7) * (TS / 4);

    const float4* p0 = (const float4*)(img);
    const float4* p1 = (const float4*)(img + PLANE);
    const float4* p2 = (const float4*)(img + 2 * PLANE);
    vf4* o0 = (vf4*)(out);
    vf4* o1 = (vf4*)(out + PLANE);
    vf4* o2 = (vf4*)(out + 2 * PLANE);

    int colv = tid & 127;
    int rsub = tid >> 7;

#pragma unroll
    for (int it = 0; it < 8; ++it) {
        int r = row0 + (it << 1) + rsub;
        size_t idx4 = (size_t)r * (WW / 4) + cb4 + colv;
        float4 a = p0[idx4];
        float4 b = p1[idx4];
        float4 c = p2[idx4];
        float4 r0, r1, r2;
        APPLY_LANE2(x)
        APPLY_LANE2(y)
        APPLY_LANE2(z)
        APPLY_LANE2(w)
        // non-temporal: out never re-read; keeps L2/L3 read-only for img residency
        // (R8 ablation: regular stores cost +20 us via img eviction)
        vf4 v0 = {r0.x, r0.y, r0.z, r0.w};
        vf4 v1 = {r1.x, r1.y, r1.z, r1.w};
        vf4 v2 = {r2.x, r2.y, r2.z, r2.w};
        __builtin_nontemporal_store(v0, &o0[idx4]);
        __builtin_nontemporal_store(v1, &o1[idx4]);
        __builtin_nontemporal_store(v2, &o2[idx4]);
    }
}

// ==================== FALLBACK PATH (ws too small: atomics + memset) ====================

__global__ __launch_bounds__(256) void k_hist_a(const float* __restrict__ img,
                                                unsigned* __restrict__ ghist,
                                                unsigned* __restrict__ minu,
                                                unsigned* __restrict__ maxu) {
    __shared__ unsigned shf[NBINS];
    __shared__ float smin[4], smax[4];
    int tid = threadIdx.x;
    shf[tid] = 0u;
    __syncthreads();
    unsigned* sh = shf;
    int bx = blockIdx.x;
    int t = bx >> 5;
    int chunk = bx & 31;
    int row0 = (t >> 3) * TS + chunk * 16;
    int cb4 = (t & 7) * (TS / 4);
    const float4* p0 = (const float4*)(img);
    const float4* p1 = (const float4*)(img + PLANE);
    const float4* p2 = (const float4*)(img + 2 * PLANE);
    int colv = tid & 127;
    int rsub = tid >> 7;
    float vmin = 1e30f, vmax = -1e30f;
#pragma unroll
    for (int it = 0; it < 8; ++it) {
        int r = row0 + (it << 1) + rsub;
        size_t idx4 = (size_t)r * (WW / 4) + cb4 + colv;
        float4 a = p0[idx4];
        float4 b = p1[idx4];
        float4 c = p2[idx4];
        HIST_LANE(x)
        HIST_LANE(y)
        HIST_LANE(z)
        HIST_LANE(w)
    }
    float wmn = wred_min(vmin), wmx = wred_max(vmax);
    if ((tid & 63) == 0) { smin[tid >> 6] = wmn; smax[tid >> 6] = wmx; }
    __syncthreads();
    if (tid == 0) {
        float m = fminf(fminf(smin[0], smin[1]), fminf(smin[2], smin[3]));
        float M = fmaxf(fmaxf(smax[0], smax[1]), fmaxf(smax[2], smax[3]));
        atomicMax(&minu[t], 0x3F800000u - __float_as_uint(m));
        atomicMax(&maxu[t], __float_as_uint(M));
    }
    atomicAdd(&ghist[t * NBINS + tid], shf[tid]);
}

__global__ __launch_bounds__(256) void k_cdf_a(const unsigned* __restrict__ ghist,
                                               const unsigned* __restrict__ minu,
                                               const unsigned* __restrict__ maxu,
                                               const float* __restrict__ alphas,
                                               float* __restrict__ cdfa,
                                               float* __restrict__ params) {
    __shared__ float wtot[4];
    __shared__ float wsums[4];
    int t = blockIdx.x, tid = threadIdx.x;
    float h = (float)ghist[t * NBINS + tid];
    const float cl = 4096.0f;
    float ex = fmaxf(h - cl, 0.0f);
    float w = wred_sum(ex);
    if ((tid & 63) == 0) wsums[tid >> 6] = w;
    __syncthreads();
    float excess = wsums[0] + wsums[1] + wsums[2] + wsums[3];
    float hc = fminf(h, cl) + excess / 256.0f;

    int lane = tid & 63, wv = tid >> 6;
    float v = hc;
#pragma unroll
    for (int off = 1; off < 64; off <<= 1) {
        float u = __shfl_up(v, off, 64);
        if (lane >= off) v += u;
    }
    if (lane == 63) wtot[wv] = v;
    __syncthreads();
    float base = 0.0f;
    if (wv > 0) base += wtot[0];
    if (wv > 1) base += wtot[1];
    if (wv > 2) base += wtot[2];
    float cdf = base + v;
    float total = ((wtot[0] + wtot[1]) + wtot[2]) + wtot[3];

    float alpha = 0.5f + 0.5f * alphas[t];
    cdfa[t * NBINS + tid] = alpha * (cdf / total);

    if (tid == 0) {
        float tmin = __uint_as_float(0x3F800000u - minu[t]);
        float tmax = __uint_as_float(maxu[t]);
        bool valid = tmin < tmax;
        params[t * 4 + 0] = tmin;
        params[t * 4 + 1] = valid ? (tmax - tmin) : 1.0f;
        params[t * 4 + 2] = 1.0f - alpha;
        params[t * 4 + 3] = valid ? 1.0f : 0.0f;
    }
}

extern "C" void kernel_launch(void* const* d_in, const int* in_sizes, int n_in,
                              void* d_out, int out_size, void* d_ws, size_t ws_size,
                              hipStream_t stream) {
    const float* img = (const float*)d_in[0];
    const float* alphas = (const float*)d_in[1];
    float* out = (float*)d_out;

    // partials layout (4B units):
    // part[2048*256] | pmin[2048] | pmax[2048] | cdfa[64*256] | params[64*4]
    const size_t need = ((size_t)NBLK * NBINS + 2 * NBLK + NT * NBINS + NT * 4) * 4;

    if (ws_size >= need) {
        unsigned* part = (unsigned*)d_ws;
        float* pmin = (float*)(part + (size_t)NBLK * NBINS);
        float* pmax = pmin + NBLK;
        float* cdfa = pmax + NBLK;
        float* params = cdfa + NT * NBINS;

        k_hist_p<<<NBLK, 256, 0, stream>>>(img, part, pmin, pmax);
        k_cdf_p<<<NT, NBINS, 0, stream>>>(part, pmin, pmax, alphas, cdfa, params);
        k_apply_t<<<NBLK, 256, 0, stream>>>(img, out, cdfa, params);
    } else {
        // fallback: hist[64*256] | minu[64] | maxu[64] | pad[64] | cdfa[64*256] | params[64*4]
        unsigned* hist = (unsigned*)d_ws;
        unsigned* minu = hist + NT * NBINS;
        unsigned* maxu = minu + NT;
        float* cdfa = (float*)(maxu + 2 * NT);
        float* params = cdfa + NT * NBINS;

        (void)hipMemsetAsync(d_ws, 0, (size_t)(NT * NBINS + 3 * NT) * 4, stream);
        k_hist_a<<<NBLK, 256, 0, stream>>>(img, hist, minu, maxu);
        k_cdf_a<<<NT, NBINS, 0, stream>>>(hist, minu, maxu, alphas, cdfa, params);
        k_apply_t<<<NBLK, 256, 0, stream>>>(img, out, cdfa, params);
    }
}